// Round 8
// baseline (329.930 us; speedup 1.0000x reference)
//
#include <hip/hip_runtime.h>

#define N_NODES 50000
#define N_EDGES 800000
#define N_GRAPHS 512
#define CAP 48   // max tracked degree; Poisson(16): P(deg>=48) per node ~1e-11, negligible

typedef __bf16 bf16x8 __attribute__((ext_vector_type(8)));
typedef float f32x4 __attribute__((ext_vector_type(4)));
typedef unsigned short u16;
typedef unsigned int u32;

__device__ __forceinline__ u16 f2bf(float f) {
    union { float f; u32 i; } v; v.f = f;
    u32 r = v.i + 0x7fffu + ((v.i >> 16) & 1u);
    return (u16)(r >> 16);
}
__device__ __forceinline__ float bf2f(u16 u) {
    union { u32 i; float f; } v; v.i = ((u32)u) << 16; return v.f;
}

// ---------------- mega prep: slot fill (latency-bound) overlapped with conversions (BW-bound) ----------------
__global__ void k_prep(const int* __restrict__ ei, int* __restrict__ cnt, u16* __restrict__ slots,
                       const float* __restrict__ X, u16* __restrict__ XB,
                       const float* __restrict__ W1a, const float* __restrict__ W1b,
                       const float* __restrict__ W2a, const float* __restrict__ W2b,
                       u16* __restrict__ T1a, u16* __restrict__ T1b,
                       u16* __restrict__ T2a, u16* __restrict__ T2b,
                       int E, int n4) {
    int bid = blockIdx.x;
    if (bid < 3125) {
        int e = bid * 256 + threadIdx.x;
        if (e < E) {
            int s = ei[e];
            int d = ei[E + e];
            int p = atomicAdd(&cnt[d * 4], 1);
            if (p < CAP) slots[(size_t)d * CAP + p] = (u16)s;
        }
    } else if (bid < 9375) {
        int i = (bid - 3125) * 256 + threadIdx.x;
        if (i < n4) {
            float4 v = ((const float4*)X)[i];
            ushort4 o;
            o.x = f2bf(v.x); o.y = f2bf(v.y); o.z = f2bf(v.z); o.w = f2bf(v.w);
            ((ushort4*)XB)[i] = o;
        }
    } else {
        int b2 = bid - 9375;                    // 0..255
        int widx = b2 >> 6;                     // which weight
        int i = (b2 & 63) * 256 + threadIdx.x;  // 0..16383
        const float* W = widx == 0 ? W1a : widx == 1 ? W1b : widx == 2 ? W2a : W2b;
        u16* T = widx == 0 ? T1a : widx == 1 ? T1b : widx == 2 ? T2a : T2b;
        int k = i >> 7, n = i & 127;
        T[n * 128 + k] = f2bf(W[k * 128 + n]);
    }
}

// ---------------- fused agg + MLP ----------------
// Per 64-row tile: gather z = x[n] + sum_nbr x[nbr] straight into swizzled LDS,
// then H = relu( relu(z@Wa+ba) @ Wb + bb ) via bf16 MFMA. No intermediate z buffer.
__global__ __launch_bounds__(256, 3)
void k_fmlp(const u16* __restrict__ X, const int* __restrict__ cnt, const u16* __restrict__ slots,
            const u16* __restrict__ WaT, const float* __restrict__ ba,
            const u16* __restrict__ WbT, const float* __restrict__ bb,
            u16* __restrict__ H, int N) {
    __shared__ u16 smZ[64 * 128];   // 16 KB: z tile, later mid tile
    __shared__ u16 smW[128 * 128];  // 32 KB: Wa, later Wb
    uint4* smZ4 = (uint4*)smZ;
    uint4* smW4 = (uint4*)smW;

    const int tid = threadIdx.x;
    const int lane = tid & 63, wv = tid >> 6;
    const int q = lane >> 4, m = lane & 15;
    const int row0 = blockIdx.x * 64;

    // stage Wa
    for (int i = tid; i < 2048; i += 256) {
        int r = i >> 4, c4 = i & 15;
        smW4[r * 16 + (c4 ^ (r & 15))] = ((const uint4*)WaT)[i];
    }

    // gather phase: wave wv owns tile rows [16*wv, 16*wv+16)
    const u32* X2 = (const u32*)X;
#pragma unroll 2
    for (int rr = 0; rr < 16; ++rr) {
        int r = wv * 16 + rr;
        int node = row0 + r;
        float ax = 0.f, ay = 0.f;
        if (node < N) {
            u32 v = X2[(size_t)node * 64 + lane];
            ax = bf2f((u16)(v & 0xffff));
            ay = bf2f((u16)(v >> 16));
            int deg = cnt[node * 4];
            if (deg > CAP) deg = CAP;
            int idx = (lane < deg) ? (int)slots[(size_t)node * CAP + lane] : 0;
            int j = 0;
            for (; j + 16 <= deg; j += 16) {
                u32 t[16];
#pragma unroll
                for (int u = 0; u < 16; ++u)
                    t[u] = X2[(size_t)__shfl(idx, j + u) * 64 + lane];
                float sx = 0.f, sy = 0.f;
#pragma unroll
                for (int u = 0; u < 16; ++u) {
                    sx += bf2f((u16)(t[u] & 0xffff));
                    sy += bf2f((u16)(t[u] >> 16));
                }
                ax += sx; ay += sy;
            }
            for (; j + 4 <= deg; j += 4) {
                u32 t0 = X2[(size_t)__shfl(idx, j    ) * 64 + lane];
                u32 t1 = X2[(size_t)__shfl(idx, j + 1) * 64 + lane];
                u32 t2 = X2[(size_t)__shfl(idx, j + 2) * 64 + lane];
                u32 t3 = X2[(size_t)__shfl(idx, j + 3) * 64 + lane];
                ax += bf2f((u16)(t0 & 0xffff)) + bf2f((u16)(t1 & 0xffff))
                    + bf2f((u16)(t2 & 0xffff)) + bf2f((u16)(t3 & 0xffff));
                ay += bf2f((u16)(t0 >> 16)) + bf2f((u16)(t1 >> 16))
                    + bf2f((u16)(t2 >> 16)) + bf2f((u16)(t3 >> 16));
            }
            for (; j < deg; ++j) {
                u32 u = X2[(size_t)__shfl(idx, j) * 64 + lane];
                ax += bf2f((u16)(u & 0xffff));
                ay += bf2f((u16)(u >> 16));
            }
        }
        // write z row into swizzled LDS: lane holds dims 2*lane, 2*lane+1
        u32 pk = (((u32)f2bf(ay)) << 16) | (u32)f2bf(ax);
        ((u32*)smZ)[(r * 16 + ((lane >> 2) ^ (r & 15))) * 4 + (lane & 3)] = pk;
    }
    __syncthreads();

    // GEMM1: mid = relu(z @ Wa + ba); wave wv computes tile rows [16wv,16wv+16)
    f32x4 acc[8];
#pragma unroll
    for (int nt = 0; nt < 8; ++nt) acc[nt] = (f32x4){0.f, 0.f, 0.f, 0.f};
    for (int kt = 0; kt < 4; ++kt) {
        int r = wv * 16 + m;
        bf16x8 a = *(const bf16x8*)(smZ4 + (r * 16 + ((kt * 4 + q) ^ (r & 15))));
        for (int nt = 0; nt < 8; ++nt) {
            int n = nt * 16 + m;
            bf16x8 b = *(const bf16x8*)(smW4 + (n * 16 + ((kt * 4 + q) ^ (n & 15))));
            acc[nt] = __builtin_amdgcn_mfma_f32_16x16x32_bf16(a, b, acc[nt], 0, 0, 0);
        }
    }
    __syncthreads();

    // stage Wb (overwrites Wa) and write relu(mid) into smZ
    for (int i = tid; i < 2048; i += 256) {
        int r = i >> 4, c4 = i & 15;
        smW4[r * 16 + (c4 ^ (r & 15))] = ((const uint4*)WbT)[i];
    }
    for (int nt = 0; nt < 8; ++nt) {
        int col = nt * 16 + m;
        float bias = ba[col];
        int c4 = col >> 3, ci = col & 7;
#pragma unroll
        for (int r2 = 0; r2 < 4; ++r2) {
            int row = wv * 16 + q * 4 + r2;  // C-layout: row=(lane>>4)*4+reg
            float x = acc[nt][r2] + bias;
            x = x > 0.f ? x : 0.f;
            smZ[(row * 16 + (c4 ^ (row & 15))) * 8 + ci] = f2bf(x);
        }
    }
    __syncthreads();

    // GEMM2: out = relu(mid @ Wb + bb)
    f32x4 acc2[8];
#pragma unroll
    for (int nt = 0; nt < 8; ++nt) acc2[nt] = (f32x4){0.f, 0.f, 0.f, 0.f};
    for (int kt = 0; kt < 4; ++kt) {
        int r = wv * 16 + m;
        bf16x8 a = *(const bf16x8*)(smZ4 + (r * 16 + ((kt * 4 + q) ^ (r & 15))));
        for (int nt = 0; nt < 8; ++nt) {
            int n = nt * 16 + m;
            bf16x8 b = *(const bf16x8*)(smW4 + (n * 16 + ((kt * 4 + q) ^ (n & 15))));
            acc2[nt] = __builtin_amdgcn_mfma_f32_16x16x32_bf16(a, b, acc2[nt], 0, 0, 0);
        }
    }
    for (int nt = 0; nt < 8; ++nt) {
        int col = nt * 16 + m;
        float bias = bb[col];
#pragma unroll
        for (int r2 = 0; r2 < 4; ++r2) {
            int grow = row0 + wv * 16 + q * 4 + r2;
            if (grow < N) {
                float x = acc2[nt][r2] + bias;
                H[(size_t)grow * 128 + col] = f2bf(x > 0.f ? x : 0.f);
            }
        }
    }
}

// ---------------- fused pool+FC: out[g] = relu( (sum_{n in g} h[n]) @ Wfc + bfc ) ----------------
__global__ __launch_bounds__(256)
void k_poolfc(const u16* __restrict__ H, const int* __restrict__ batch,
              const float* __restrict__ W, const float* __restrict__ bias,
              float* __restrict__ O, int N) {
    int g = blockIdx.x;
    int tid = threadIdx.x;
    int lane = tid & 63, wv = tid >> 6;
    int lo = 0, hi = N;
    while (lo < hi) { int mid = (lo + hi) >> 1; if (batch[mid] < g) lo = mid + 1; else hi = mid; }
    int lo2 = lo; hi = N;
    while (lo2 < hi) { int mid = (lo2 + hi) >> 1; if (batch[mid] < g + 1) lo2 = mid + 1; else hi = mid; }
    const u32* H2 = (const u32*)H;
    float ax = 0.f, ay = 0.f;
    for (int n = lo + wv; n < lo2; n += 4) {
        u32 u = H2[(size_t)n * 64 + lane];
        ax += bf2f((u16)(u & 0xffff));
        ay += bf2f((u16)(u >> 16));
    }
    __shared__ float part[4][128];
    part[wv][lane * 2] = ax;
    part[wv][lane * 2 + 1] = ay;
    __syncthreads();
    __shared__ float gs[128];
    if (tid < 128) {
        gs[tid] = part[0][tid] + part[1][tid] + part[2][tid] + part[3][tid];
    }
    __syncthreads();
    if (tid < 128) {
        float acc = bias[tid];
        for (int k = 0; k < 128; ++k)
            acc += gs[k] * W[k * 128 + tid];
        O[g * 128 + tid] = acc > 0.f ? acc : 0.f;
    }
}

extern "C" void kernel_launch(void* const* d_in, const int* in_sizes, int n_in,
                              void* d_out, int out_size, void* d_ws, size_t ws_size,
                              hipStream_t stream) {
    const int N = N_NODES, E = N_EDGES, NG = N_GRAPHS;

    const float* x   = (const float*)d_in[0];
    const int* ei    = (const int*)d_in[1];
    const int* batch = (const int*)d_in[2];
    const float* W1a = (const float*)d_in[3];
    const float* b1a = (const float*)d_in[4];
    const float* W1b = (const float*)d_in[5];
    const float* b1b = (const float*)d_in[6];
    const float* W2a = (const float*)d_in[7];
    const float* b2a = (const float*)d_in[8];
    const float* W2b = (const float*)d_in[9];
    const float* b2b = (const float*)d_in[10];
    const float* Wfc = (const float*)d_in[11];
    const float* bfc = (const float*)d_in[12];
    float* out = (float*)d_out;

    char* w = (char*)d_ws;
    int* cnt    = (int*)(w + 0x0000000);   // 50000*4 ints = 800 KB
    u16* slots  = (u16*)(w + 0x0100000);   // 50000*48*2B = 4.8 MB
    u16* xb     = (u16*)(w + 0x0600000);   // 12.8 MB
    u16* hb     = (u16*)(w + 0x1300000);   // 12.8 MB (layer-1 output)
    u16* h2     = (u16*)(w + 0x2000000);   // 12.8 MB (layer-2 output)
    u16* T1a    = (u16*)(w + 0x2D40000);   // 32 KB each
    u16* T1b    = (u16*)(w + 0x2D48000);
    u16* T2a    = (u16*)(w + 0x2D50000);
    u16* T2b    = (u16*)(w + 0x2D58000);

    hipMemsetAsync(cnt, 0, (size_t)N * 4 * sizeof(int), stream);

    const int n4 = N * 128 / 4;            // 1.6M float4 groups
    k_prep<<<9631, 256, 0, stream>>>(ei, cnt, slots, x, xb, W1a, W1b, W2a, W2b,
                                     T1a, T1b, T2a, T2b, E, n4);

    const int FB = (N + 63) / 64;          // 782 blocks

    k_fmlp<<<FB, 256, 0, stream>>>(xb, cnt, slots, T1a, b1a, T1b, b1b, hb, N);
    k_fmlp<<<FB, 256, 0, stream>>>(hb, cnt, slots, T2a, b2a, T2b, b2b, h2, N);

    k_poolfc<<<NG, 256, 0, stream>>>(h2, batch, Wfc, bfc, out, N);
}

// Round 9
// 236.351 us; speedup vs baseline: 1.3959x; 1.3959x over previous
//
#include <hip/hip_runtime.h>

#define N_NODES 50000
#define N_EDGES 800000
#define N_GRAPHS 512
#define CAP 48   // max tracked degree; Poisson(16): P(deg>=48) per node ~1e-11, negligible

typedef __bf16 bf16x8 __attribute__((ext_vector_type(8)));
typedef float f32x4 __attribute__((ext_vector_type(4)));
typedef unsigned short u16;
typedef unsigned int u32;

__device__ __forceinline__ u16 f2bf(float f) {
    union { float f; u32 i; } v; v.f = f;
    u32 r = v.i + 0x7fffu + ((v.i >> 16) & 1u);
    return (u16)(r >> 16);
}
__device__ __forceinline__ float bf2f(u16 u) {
    union { u32 i; float f; } v; v.i = ((u32)u) << 16; return v.f;
}

// ---------------- mega prep: slot fill (latency-bound) overlapped with conversions (BW-bound) ----------------
__global__ void k_prep(const int* __restrict__ ei, int* __restrict__ cnt, u16* __restrict__ slots,
                       const float* __restrict__ X, u16* __restrict__ XB,
                       const float* __restrict__ W1a, const float* __restrict__ W1b,
                       const float* __restrict__ W2a, const float* __restrict__ W2b,
                       u16* __restrict__ T1a, u16* __restrict__ T1b,
                       u16* __restrict__ T2a, u16* __restrict__ T2b,
                       int E, int n4) {
    int bid = blockIdx.x;
    if (bid < 3125) {
        int e = bid * 256 + threadIdx.x;
        if (e < E) {
            int s = ei[e];
            int d = ei[E + e];
            int p = atomicAdd(&cnt[d * 4], 1);
            if (p < CAP) slots[(size_t)d * CAP + p] = (u16)s;
        }
    } else if (bid < 9375) {
        int i = (bid - 3125) * 256 + threadIdx.x;
        if (i < n4) {
            float4 v = ((const float4*)X)[i];
            ushort4 o;
            o.x = f2bf(v.x); o.y = f2bf(v.y); o.z = f2bf(v.z); o.w = f2bf(v.w);
            ((ushort4*)XB)[i] = o;
        }
    } else {
        int b2 = bid - 9375;                    // 0..255
        int widx = b2 >> 6;                     // which weight
        int i = (b2 & 63) * 256 + threadIdx.x;  // 0..16383
        const float* W = widx == 0 ? W1a : widx == 1 ? W1b : widx == 2 ? W2a : W2b;
        u16* T = widx == 0 ? T1a : widx == 1 ? T1b : widx == 2 ? T2a : T2b;
        int k = i >> 7, n = i & 127;
        T[n * 128 + k] = f2bf(W[k * 128 + n]);
    }
}

// ---------------- aggregation: z[n] = x[n] + sum_{nbr} x[nbr] ----------------
// bf16 in/out, f32 accumulate. One wave per node (VGPR-light, max occupancy).
__global__ void k_agg(const u16* __restrict__ X, const int* __restrict__ cnt,
                      const u16* __restrict__ slots, u16* __restrict__ Z, int N) {
    int wid = (blockIdx.x * blockDim.x + threadIdx.x) >> 6;
    if (wid >= N) return;
    int lane = threadIdx.x & 63;
    const u32* X2 = (const u32*)X;
    u32 v = X2[(size_t)wid * 64 + lane];
    float ax = bf2f((u16)(v & 0xffff));
    float ay = bf2f((u16)(v >> 16));
    int deg = cnt[wid * 4];
    if (deg > CAP) deg = CAP;
    int idx = (lane < deg) ? (int)slots[(size_t)wid * CAP + lane] : 0;
    int j = 0;
    for (; j + 16 <= deg; j += 16) {
        u32 t[16];
#pragma unroll
        for (int u = 0; u < 16; ++u)
            t[u] = X2[(size_t)__shfl(idx, j + u) * 64 + lane];
        float sx = 0.f, sy = 0.f;
#pragma unroll
        for (int u = 0; u < 16; ++u) {
            sx += bf2f((u16)(t[u] & 0xffff));
            sy += bf2f((u16)(t[u] >> 16));
        }
        ax += sx; ay += sy;
    }
    for (; j + 4 <= deg; j += 4) {
        u32 t0 = X2[(size_t)__shfl(idx, j    ) * 64 + lane];
        u32 t1 = X2[(size_t)__shfl(idx, j + 1) * 64 + lane];
        u32 t2 = X2[(size_t)__shfl(idx, j + 2) * 64 + lane];
        u32 t3 = X2[(size_t)__shfl(idx, j + 3) * 64 + lane];
        ax += bf2f((u16)(t0 & 0xffff)) + bf2f((u16)(t1 & 0xffff))
            + bf2f((u16)(t2 & 0xffff)) + bf2f((u16)(t3 & 0xffff));
        ay += bf2f((u16)(t0 >> 16)) + bf2f((u16)(t1 >> 16))
            + bf2f((u16)(t2 >> 16)) + bf2f((u16)(t3 >> 16));
    }
    for (; j < deg; ++j) {
        u32 u = X2[(size_t)__shfl(idx, j) * 64 + lane];
        ax += bf2f((u16)(u & 0xffff));
        ay += bf2f((u16)(u >> 16));
    }
    ((u32*)Z)[(size_t)wid * 64 + lane] = (((u32)f2bf(ay)) << 16) | (u32)f2bf(ax);
}

// ---------------- fused MLP (bf16 MFMA): H = relu( relu(Z@Wa+ba) @ Wb + bb ) ----------------
__global__ __launch_bounds__(256, 1)
void k_mlp(const u16* __restrict__ Z, const u16* __restrict__ WaT,
           const float* __restrict__ ba, const u16* __restrict__ WbT,
           const float* __restrict__ bb, u16* __restrict__ H, int N) {
    __shared__ u16 smZ[128 * 128];  // z tile, later reused for mid tile
    __shared__ u16 smW[128 * 128];  // Wa, later Wb
    uint4* smZ4 = (uint4*)smZ;
    uint4* smW4 = (uint4*)smW;

    const int tid = threadIdx.x;
    const int lane = tid & 63, wv = tid >> 6;
    const int q = lane >> 4, m = lane & 15;
    const int row0 = blockIdx.x * 128;

    for (int i = tid; i < 2048; i += 256) {
        int r = i >> 4, c4 = i & 15;
        smW4[r * 16 + (c4 ^ (r & 15))] = ((const uint4*)WaT)[i];
    }
    for (int i = tid; i < 2048; i += 256) {
        int r = i >> 4, c4 = i & 15;
        int gr = row0 + r;
        uint4 v = make_uint4(0u, 0u, 0u, 0u);
        if (gr < N) v = ((const uint4*)Z)[(size_t)gr * 16 + c4];
        smZ4[r * 16 + (c4 ^ (r & 15))] = v;
    }
    __syncthreads();

    f32x4 acc[2][8];
    for (int rt = 0; rt < 2; ++rt)
        for (int nt = 0; nt < 8; ++nt)
            acc[rt][nt] = (f32x4){0.f, 0.f, 0.f, 0.f};
    for (int kt = 0; kt < 4; ++kt) {
        bf16x8 a[2];
        for (int rt = 0; rt < 2; ++rt) {
            int r = wv * 32 + rt * 16 + m;
            a[rt] = *(const bf16x8*)(smZ4 + (r * 16 + ((kt * 4 + q) ^ (r & 15))));
        }
        for (int nt = 0; nt < 8; ++nt) {
            int n = nt * 16 + m;
            bf16x8 bfr = *(const bf16x8*)(smW4 + (n * 16 + ((kt * 4 + q) ^ (n & 15))));
            for (int rt = 0; rt < 2; ++rt)
                acc[rt][nt] = __builtin_amdgcn_mfma_f32_16x16x32_bf16(a[rt], bfr, acc[rt][nt], 0, 0, 0);
        }
    }
    __syncthreads();

    for (int i = tid; i < 2048; i += 256) {
        int r = i >> 4, c4 = i & 15;
        smW4[r * 16 + (c4 ^ (r & 15))] = ((const uint4*)WbT)[i];
    }
    for (int nt = 0; nt < 8; ++nt) {
        int col = nt * 16 + m;
        float bias = ba[col];
        int c4 = col >> 3, ci = col & 7;
        for (int rt = 0; rt < 2; ++rt)
            for (int r2 = 0; r2 < 4; ++r2) {
                int row = wv * 32 + rt * 16 + q * 4 + r2;  // C-layout: row=(lane>>4)*4+reg
                float x = acc[rt][nt][r2] + bias;
                x = x > 0.f ? x : 0.f;
                smZ[(row * 16 + (c4 ^ (row & 15))) * 8 + ci] = f2bf(x);
            }
    }
    __syncthreads();

    f32x4 acc2[2][8];
    for (int rt = 0; rt < 2; ++rt)
        for (int nt = 0; nt < 8; ++nt)
            acc2[rt][nt] = (f32x4){0.f, 0.f, 0.f, 0.f};
    for (int kt = 0; kt < 4; ++kt) {
        bf16x8 a[2];
        for (int rt = 0; rt < 2; ++rt) {
            int r = wv * 32 + rt * 16 + m;
            a[rt] = *(const bf16x8*)(smZ4 + (r * 16 + ((kt * 4 + q) ^ (r & 15))));
        }
        for (int nt = 0; nt < 8; ++nt) {
            int n = nt * 16 + m;
            bf16x8 bfr = *(const bf16x8*)(smW4 + (n * 16 + ((kt * 4 + q) ^ (n & 15))));
            for (int rt = 0; rt < 2; ++rt)
                acc2[rt][nt] = __builtin_amdgcn_mfma_f32_16x16x32_bf16(a[rt], bfr, acc2[rt][nt], 0, 0, 0);
        }
    }
    for (int nt = 0; nt < 8; ++nt) {
        int col = nt * 16 + m;
        float bias = bb[col];
        for (int rt = 0; rt < 2; ++rt)
            for (int r2 = 0; r2 < 4; ++r2) {
                int row = row0 + wv * 32 + rt * 16 + q * 4 + r2;
                if (row < N) {
                    float x = acc2[rt][nt][r2] + bias;
                    H[(size_t)row * 128 + col] = f2bf(x > 0.f ? x : 0.f);
                }
            }
    }
}

// ---------------- layer-2 MLP with fused global-add-pool epilogue ----------------
// Same GEMMs as k_mlp, but H2 never leaves the block: bf16 tile -> LDS,
// segmented column-scan over sorted batch ids, ~1-2 atomicAdds per run into G.
__global__ __launch_bounds__(256, 1)
void k_mlp2(const u16* __restrict__ Z, const u16* __restrict__ WaT,
            const float* __restrict__ ba, const u16* __restrict__ WbT,
            const float* __restrict__ bb, const int* __restrict__ batch,
            float* __restrict__ G, int N) {
    __shared__ u16 smZ[128 * 128];
    __shared__ u16 smW[128 * 128];
    __shared__ int sb[128];
    uint4* smZ4 = (uint4*)smZ;
    uint4* smW4 = (uint4*)smW;

    const int tid = threadIdx.x;
    const int lane = tid & 63, wv = tid >> 6;
    const int q = lane >> 4, m = lane & 15;
    const int row0 = blockIdx.x * 128;

    if (tid < 128) sb[tid] = (row0 + tid < N) ? batch[row0 + tid] : -1;

    for (int i = tid; i < 2048; i += 256) {
        int r = i >> 4, c4 = i & 15;
        smW4[r * 16 + (c4 ^ (r & 15))] = ((const uint4*)WaT)[i];
    }
    for (int i = tid; i < 2048; i += 256) {
        int r = i >> 4, c4 = i & 15;
        int gr = row0 + r;
        uint4 v = make_uint4(0u, 0u, 0u, 0u);
        if (gr < N) v = ((const uint4*)Z)[(size_t)gr * 16 + c4];
        smZ4[r * 16 + (c4 ^ (r & 15))] = v;
    }
    __syncthreads();

    f32x4 acc[2][8];
    for (int rt = 0; rt < 2; ++rt)
        for (int nt = 0; nt < 8; ++nt)
            acc[rt][nt] = (f32x4){0.f, 0.f, 0.f, 0.f};
    for (int kt = 0; kt < 4; ++kt) {
        bf16x8 a[2];
        for (int rt = 0; rt < 2; ++rt) {
            int r = wv * 32 + rt * 16 + m;
            a[rt] = *(const bf16x8*)(smZ4 + (r * 16 + ((kt * 4 + q) ^ (r & 15))));
        }
        for (int nt = 0; nt < 8; ++nt) {
            int n = nt * 16 + m;
            bf16x8 bfr = *(const bf16x8*)(smW4 + (n * 16 + ((kt * 4 + q) ^ (n & 15))));
            for (int rt = 0; rt < 2; ++rt)
                acc[rt][nt] = __builtin_amdgcn_mfma_f32_16x16x32_bf16(a[rt], bfr, acc[rt][nt], 0, 0, 0);
        }
    }
    __syncthreads();

    for (int i = tid; i < 2048; i += 256) {
        int r = i >> 4, c4 = i & 15;
        smW4[r * 16 + (c4 ^ (r & 15))] = ((const uint4*)WbT)[i];
    }
    for (int nt = 0; nt < 8; ++nt) {
        int col = nt * 16 + m;
        float bias = ba[col];
        int c4 = col >> 3, ci = col & 7;
        for (int rt = 0; rt < 2; ++rt)
            for (int r2 = 0; r2 < 4; ++r2) {
                int row = wv * 32 + rt * 16 + q * 4 + r2;
                float x = acc[rt][nt][r2] + bias;
                x = x > 0.f ? x : 0.f;
                smZ[(row * 16 + (c4 ^ (row & 15))) * 8 + ci] = f2bf(x);
            }
    }
    __syncthreads();

    f32x4 acc2[2][8];
    for (int rt = 0; rt < 2; ++rt)
        for (int nt = 0; nt < 8; ++nt)
            acc2[rt][nt] = (f32x4){0.f, 0.f, 0.f, 0.f};
    for (int kt = 0; kt < 4; ++kt) {
        bf16x8 a[2];
        for (int rt = 0; rt < 2; ++rt) {
            int r = wv * 32 + rt * 16 + m;
            a[rt] = *(const bf16x8*)(smZ4 + (r * 16 + ((kt * 4 + q) ^ (r & 15))));
        }
        for (int nt = 0; nt < 8; ++nt) {
            int n = nt * 16 + m;
            bf16x8 bfr = *(const bf16x8*)(smW4 + (n * 16 + ((kt * 4 + q) ^ (n & 15))));
            for (int rt = 0; rt < 2; ++rt)
                acc2[rt][nt] = __builtin_amdgcn_mfma_f32_16x16x32_bf16(a[rt], bfr, acc2[rt][nt], 0, 0, 0);
        }
    }
    // epilogue: H2 tile (bf16) into wave-private LDS rows, plain row-major
    for (int nt = 0; nt < 8; ++nt) {
        int col = nt * 16 + m;
        float bias = bb[col];
        for (int rt = 0; rt < 2; ++rt)
#pragma unroll
            for (int r2 = 0; r2 < 4; ++r2) {
                int row = wv * 32 + rt * 16 + q * 4 + r2;
                float x = acc2[rt][nt][r2] + bias;
                smZ[row * 128 + col] = f2bf(x > 0.f ? x : 0.f);
            }
    }
    __syncthreads();
    // segmented pool: thread (col, half) scans 64 sorted rows, one atomic per run
    {
        int col = tid & 127, half = tid >> 7;
        int rbeg = half * 64, rend = rbeg + 64;
        float run = 0.f; int curg = -1;
        for (int r = rbeg; r < rend; ++r) {
            int gg = sb[r];
            if (gg < 0) break;
            if (gg != curg) {
                if (curg >= 0) atomicAdd(&G[curg * 128 + col], run);
                run = 0.f; curg = gg;
            }
            run += bf2f(smZ[r * 128 + col]);
        }
        if (curg >= 0) atomicAdd(&G[curg * 128 + col], run);
    }
}

// ---------------- final FC: out = relu(g @ Wfc + bfc) ----------------
__global__ void k_fc(const float* __restrict__ G, const float* __restrict__ W,
                     const float* __restrict__ bias, float* __restrict__ O) {
    __shared__ float gs[128];
    int t = threadIdx.x, gidx = blockIdx.x;
    gs[t] = G[gidx * 128 + t];
    __syncthreads();
    float acc = bias[t];
    for (int k = 0; k < 128; ++k)
        acc += gs[k] * W[k * 128 + t];
    acc = acc > 0.f ? acc : 0.f;
    O[gidx * 128 + t] = acc;
}

extern "C" void kernel_launch(void* const* d_in, const int* in_sizes, int n_in,
                              void* d_out, int out_size, void* d_ws, size_t ws_size,
                              hipStream_t stream) {
    const int N = N_NODES, E = N_EDGES, NG = N_GRAPHS;

    const float* x   = (const float*)d_in[0];
    const int* ei    = (const int*)d_in[1];
    const int* batch = (const int*)d_in[2];
    const float* W1a = (const float*)d_in[3];
    const float* b1a = (const float*)d_in[4];
    const float* W1b = (const float*)d_in[5];
    const float* b1b = (const float*)d_in[6];
    const float* W2a = (const float*)d_in[7];
    const float* b2a = (const float*)d_in[8];
    const float* W2b = (const float*)d_in[9];
    const float* b2b = (const float*)d_in[10];
    const float* Wfc = (const float*)d_in[11];
    const float* bfc = (const float*)d_in[12];
    float* out = (float*)d_out;

    char* w = (char*)d_ws;
    int* cnt    = (int*)(w + 0x0000000);   // 800 KB (stride-4 ints)
    float* g    = (float*)(w + 0x00C4000); // 256 KB — adjacent to cnt: one memset
    u16* slots  = (u16*)(w + 0x0110000);   // 4.8 MB
    u16* xb     = (u16*)(w + 0x05B0000);   // 12.8 MB (reused as z2)
    u16* zb     = (u16*)(w + 0x1280000);   // 12.8 MB
    u16* hb     = (u16*)(w + 0x1F50000);   // 12.8 MB
    u16* T1a    = (u16*)(w + 0x2C20000);   // 32 KB each
    u16* T1b    = (u16*)(w + 0x2C28000);
    u16* T2a    = (u16*)(w + 0x2C30000);
    u16* T2b    = (u16*)(w + 0x2C38000);

    hipMemsetAsync(w, 0, 0x104000, stream);   // cnt + g in one shot

    const int n4 = N * 128 / 4;
    k_prep<<<9631, 256, 0, stream>>>(ei, cnt, slots, x, xb, W1a, W1b, W2a, W2b,
                                     T1a, T1b, T2a, T2b, E, n4);

    const int AGGB = (N * 64 + 255) / 256;   // one wave per node
    const int MLPB = (N + 127) / 128;        // 391

    k_agg<<<AGGB, 256, 0, stream>>>(xb, cnt, slots, zb, N);
    k_mlp<<<MLPB, 256, 0, stream>>>(zb, T1a, b1a, T1b, b1b, hb, N);
    k_agg<<<AGGB, 256, 0, stream>>>(hb, cnt, slots, xb, N);   // xb reused as z2
    k_mlp2<<<MLPB, 256, 0, stream>>>(xb, T2a, b2a, T2b, b2b, batch, g, N);

    k_fc<<<NG, 128, 0, stream>>>(g, Wfc, bfc, out);
}